// Round 3
// baseline (840.337 us; speedup 1.0000x reference)
//
#include <hip/hip_runtime.h>
#include <math.h>

// ---------------------------------------------------------------------------
// VQ-VAE eval forward.  N=65536 points x K=1024 codes x D=64, fp32 in/out.
// Distances via f16x2 split-precision MFMA (32x32x16_f16), R2-proven numerics:
//   z = zh + 2^-12 zl', e = eh + 2^-12 el'  (lo parts pre-scaled by 4096)
//   argmax key m = (zh.eh - esq/2) + 2^-12 (zh.el' + zl'.eh)
// R3: 8-wave blocks (4 point-groups x 2 code-halves), double-buffered 64-code
// chunks with async-stage split, conflict-free [c][p] z layout, shuffle argmin.
// ---------------------------------------------------------------------------

#define QOUT_SZ  4194304            // 16*64*64*64
#define LOSS_OFF QOUT_SZ
#define IDX_OFF  (QOUT_SZ + 1)
#define PERP_OFF (QOUT_SZ + 1 + 65536)

typedef _Float16 f16x8 __attribute__((ext_vector_type(8)));
typedef _Float16 f16x4 __attribute__((ext_vector_type(4)));
typedef float    f32x16 __attribute__((ext_vector_type(16)));

// ws byte offsets
#define WS_EHI   0          // _Float16[65536] (128 KB)
#define WS_ELO   131072     // _Float16[65536] (128 KB)
#define WS_ESQ   262144     // float[1024]
#define WS_HIST  266240     // float[1024]
#define WS_LOSS  270336     // float[512]

// ---------------------------------------------------------------------------
// Fused prep: split-convert embedding (ehi/elo), esq[k]=||e_k||^2, zero hist.
// grid 64 x 256; one float4 of emb per thread.
// ---------------------------------------------------------------------------
__global__ void vq_pre(const float* __restrict__ emb,
                       _Float16* __restrict__ ehi, _Float16* __restrict__ elo,
                       float* __restrict__ esq, float* __restrict__ hist) {
    const int t = threadIdx.x;
    const int g = blockIdx.x * 256 + t;          // float4 unit 0..16383
    float4 v = ((const float4*)emb)[g];
    float xs[4] = {v.x, v.y, v.z, v.w};
    f16x4 hi, lo;
    float ss = 0.f;
#pragma unroll
    for (int j = 0; j < 4; ++j) {
        _Float16 h = (_Float16)xs[j];
        hi[j] = h;
        lo[j] = (_Float16)((xs[j] - (float)h) * 4096.0f);
        ss = fmaf(xs[j], xs[j], ss);
    }
    ((f16x4*)ehi)[g] = hi;
    ((f16x4*)elo)[g] = lo;
    // sum over the 16 threads covering one code (fixed butterfly order)
    ss += __shfl_xor(ss, 1, 64);
    ss += __shfl_xor(ss, 2, 64);
    ss += __shfl_xor(ss, 4, 64);
    ss += __shfl_xor(ss, 8, 64);
    if ((t & 15) == 0) esq[g >> 4] = ss;
    if (blockIdx.x < 4) hist[blockIdx.x * 256 + t] = 0.f;
}

// ---------------------------------------------------------------------------
// Main: 512 blocks x 512 threads (8 waves).  Block owns 128 points (2 bh
// rows).  Wave (pg,kh): pg=point-group (32 pts), kh=code-half of each chunk.
// k loop: 16 chunks x 64 codes, double-buffered, async-stage split.
// LDS: zs [64 c][128 p] fp32 (32 KB, conflict-free both sides) +
//      e dbuf 2x16 KB (XOR-swizzled) overlaid by 16 KB candidate arrays.
// ---------------------------------------------------------------------------
__launch_bounds__(512, 4)
__global__ void vq_main(const float* __restrict__ z,
                        const float* __restrict__ emb,
                        const _Float16* __restrict__ gehi,
                        const _Float16* __restrict__ gelo,
                        const float* __restrict__ gesq,
                        float* __restrict__ hist,
                        float* __restrict__ lossp,
                        float* __restrict__ out) {
    __shared__ float zs[64 * 128];                    // [c][p]  32 KB
    __shared__ __align__(16) char es[32768];          // 2 x 16 KB chunk bufs
    __shared__ int   idxs[128];
    __shared__ float redw[8];

    const int tid  = threadIdx.x;
    const int blk  = blockIdx.x;          // 0..511
    const int bh0  = blk * 2;
    const int b    = bh0 >> 6;
    const int h0   = bh0 & 63;
    const int lane = tid & 63;
    const int wv   = tid >> 6;            // 0..7
    const int pg   = wv & 3;              // point group
    const int kh   = wv >> 2;             // code half of chunk
    const int arow = lane & 31;
    const int kg   = lane >> 5;           // K-slice within MFMA

    // ---- stage z in [c][p] layout (b128 writes, conflict-free) ----
    const float* zb = z + (size_t)b * 262144 + (size_t)h0 * 64;
#pragma unroll
    for (int i = 0; i < 4; ++i) {
        int j  = tid + 512 * i;           // float4 unit 0..2047
        int w4 = j & 15;
        int u  = j >> 4;                  // 0..127
        int hf = u & 1;
        int c  = u >> 1;
        float4 v = *(const float4*)(zb + (size_t)c * 4096 + hf * 64 + w4 * 4);
        *(float4*)&zs[c * 128 + hf * 64 + w4 * 4] = v;
    }
    __syncthreads();

    // ---- issue chunk-0 staging loads + first esq early ----
    const uint4* g4h = (const uint4*)gehi;       // 16B units; chunk = 512 units
    const uint4* g4l = (const uint4*)gelo;
    const int sc = tid >> 3;                     // staged code 0..63
    const int sd = tid & 7;                      // 16B unit in row
    char* const dst0 = es + sc * 128 + ((sd * 16) ^ ((sc & 7) << 4));
    const int ccol = kh * 32 + arow;             // chunk-local code column

    uint4 vh0 = g4h[tid];
    uint4 vl0 = g4l[tid];
    float e2 = gesq[ccol];

    // ---- A fragments: transpose-read zs + f16x2 split (once) ----
    const int prow = pg * 32 + arow;
    f16x8 Ah[4], Al[4];
#pragma unroll
    for (int s = 0; s < 4; ++s) {
#pragma unroll
        for (int j = 0; j < 8; ++j) {
            int c = s * 16 + kg * 8 + j;
            float x = zs[c * 128 + prow];
            _Float16 h = (_Float16)x;
            Ah[s][j] = h;
            Al[s][j] = (_Float16)((x - (float)h) * 4096.0f);
        }
    }

    // per-lane B read offsets (buffer-relative, loop-invariant)
    int rb[4];
#pragma unroll
    for (int s = 0; s < 4; ++s)
        rb[s] = ccol * 128 + (((s * 2 + kg) * 16) ^ ((ccol & 7) << 4));

    // write chunk 0 into buf0
    *(uint4*)dst0 = vh0;
    *(uint4*)(dst0 + 8192) = vl0;
    __syncthreads();

    float best[16];
    int   besti[16];
#pragma unroll
    for (int r = 0; r < 16; ++r) { best[r] = -3.4e38f; besti[r] = 0; }

    // ---- k loop: 16 chunks of 64 codes, double-buffered ----
#pragma unroll 2
    for (int ch = 0; ch < 16; ++ch) {
        const int bo = (ch & 1) * 16384;
        uint4 nh, nl; float e2n = 0.f;
        if (ch < 15) {                        // issue next-chunk loads early
            nh  = g4h[tid + (ch + 1) * 512];
            nl  = g4l[tid + (ch + 1) * 512];
            e2n = gesq[(ch + 1) * 64 + ccol];
        }

        f32x16 ah, ax;
        const float e2i = e2 * -0.5f;
#pragma unroll
        for (int r = 0; r < 16; ++r) { ah[r] = e2i; ax[r] = 0.f; }
#pragma unroll
        for (int s = 0; s < 4; ++s) {
            f16x8 Bh = *(const f16x8*)(es + bo + rb[s]);
            f16x8 Bl = *(const f16x8*)(es + bo + rb[s] + 8192);
            ah = __builtin_amdgcn_mfma_f32_32x32x16_f16(Ah[s], Bh, ah, 0, 0, 0);
            ax = __builtin_amdgcn_mfma_f32_32x32x16_f16(Ah[s], Bl, ax, 0, 0, 0);
            ax = __builtin_amdgcn_mfma_f32_32x32x16_f16(Al[s], Bh, ax, 0, 0, 0);
        }
        const int kidx = ch * 64 + ccol;
#pragma unroll
        for (int r = 0; r < 16; ++r) {
            float m = fmaf(0x1p-12f, ax[r], ah[r]);
            if (m > best[r]) { best[r] = m; besti[r] = kidx; }
        }

        if (ch < 15) {                        // write-late half of the stage
            char* d = dst0 + ((ch + 1) & 1) * 16384;
            *(uint4*)d = nh;
            *(uint4*)(d + 8192) = nl;
            e2 = e2n;
        }
        __syncthreads();
    }

    // ---- argmin finish: 2-step butterfly (32 -> 8 cands/point/wave) ----
#pragma unroll
    for (int mask = 16; mask >= 8; mask >>= 1) {
#pragma unroll
        for (int r = 0; r < 16; ++r) {
            float ov = __shfl_xor(best[r], mask, 64);
            int   oi = __shfl_xor(besti[r], mask, 64);
            if (ov > best[r] || (ov == best[r] && oi < besti[r])) {
                best[r] = ov; besti[r] = oi;
            }
        }
    }
    float* cv = (float*)es;                   // [128][16] overlay on buf0
    int*   ci = (int*)(es + 8192);
    if (arow < 8) {
#pragma unroll
        for (int r = 0; r < 16; ++r) {
            int row = (r & 3) + 8 * (r >> 2) + 4 * kg;
            int p   = pg * 32 + row;
            cv[p * 16 + kh * 8 + arow] = best[r];
            ci[p * 16 + kh * 8 + arow] = besti[r];
        }
    }
    __syncthreads();
    if (tid < 128) {
        float bv = cv[tid * 16];
        int   bi = ci[tid * 16];
#pragma unroll
        for (int j = 1; j < 16; ++j) {
            float v  = cv[tid * 16 + j];
            int   ii = ci[tid * 16 + j];
            if (v > bv || (v == bv && ii < bi)) { bv = v; bi = ii; }  // np first-min
        }
        idxs[tid] = bi;
        atomicAdd(&hist[bi], 1.0f);           // exact int counts: deterministic
        out[(size_t)IDX_OFF + bh0 * 64 + tid] = (float)bi;
    }
    __syncthreads();

    // ---- epilogue: quantized write (coalesced over w) + loss partial ----
    const int w  = tid & 63;
    const int cq = tid >> 6;                  // 0..7 -> channels cq*8..cq*8+7
    float lsum = 0.f;
#pragma unroll
    for (int hf = 0; hf < 2; ++hf) {
        const int p   = hf * 64 + w;
        const int idx = idxs[p];
        const float* ev = emb + (size_t)idx * 64 + cq * 8;
        float4 q0 = *(const float4*)ev;
        float4 q1 = *(const float4*)(ev + 4);
        float qq[8] = {q0.x, q0.y, q0.z, q0.w, q1.x, q1.y, q1.z, q1.w};
        float* outq = out + (size_t)b * 262144 + (size_t)(h0 + hf) * 64 + w;
#pragma unroll
        for (int j = 0; j < 8; ++j) {
            int c = cq * 8 + j;
            float zv = zs[c * 128 + p];
            outq[(size_t)c * 4096] = qq[j];
            float d = qq[j] - zv;
            lsum = fmaf(d, d, lsum);
        }
    }
#pragma unroll
    for (int off = 32; off > 0; off >>= 1)
        lsum += __shfl_xor(lsum, off, 64);
    if (lane == 0) redw[wv] = lsum;
    __syncthreads();
    if (tid == 0) {
        float s = 0.f;
#pragma unroll
        for (int i = 0; i < 8; ++i) s += redw[i];
        lossp[blk] = s;
    }
}

// ---------------------------------------------------------------------------
// Finalize: loss + perplexity, fixed-order tree. 1 x 1024.
// ---------------------------------------------------------------------------
__global__ void vq_fin(const float* __restrict__ hist,
                       const float* __restrict__ lossp,
                       float* __restrict__ out) {
    __shared__ float sh[1024];
    __shared__ float sl[1024];
    int t = threadIdx.x;
    float hc = hist[t];
    float p  = hc * (1.0f / 65536.0f);
    sh[t] = p * logf(p + 1e-10f);
    sl[t] = (t < 512) ? lossp[t] : 0.f;
    __syncthreads();
    for (int s = 512; s > 0; s >>= 1) {
        if (t < s) { sh[t] += sh[t + s]; sl[t] += sl[t + s]; }
        __syncthreads();
    }
    if (t == 0) {
        out[LOSS_OFF] = 0.25f * sl[0] / (float)QOUT_SZ;
        out[PERP_OFF] = expf(-sh[0]);
    }
}

extern "C" void kernel_launch(void* const* d_in, const int* in_sizes, int n_in,
                              void* d_out, int out_size, void* d_ws, size_t ws_size,
                              hipStream_t stream) {
    const float* z   = (const float*)d_in[0];   // [16,64,64,64] fp32 NCHW
    const float* emb = (const float*)d_in[1];   // [1024,64] fp32
    float* out = (float*)d_out;
    char*  ws  = (char*)d_ws;

    _Float16* ehi   = (_Float16*)(ws + WS_EHI);
    _Float16* elo   = (_Float16*)(ws + WS_ELO);
    float*    esq   = (float*)(ws + WS_ESQ);
    float*    hist  = (float*)(ws + WS_HIST);
    float*    lossp = (float*)(ws + WS_LOSS);

    vq_pre<<<64, 256, 0, stream>>>(emb, ehi, elo, esq, hist);
    vq_main<<<512, 512, 0, stream>>>(z, emb, ehi, elo, esq, hist, lossp, out);
    vq_fin<<<1, 1024, 0, stream>>>(hist, lossp, out);
}

// Round 4
// 67.547 us; speedup vs baseline: 12.4408x; 12.4408x over previous
//
#include <hip/hip_runtime.h>
#include <math.h>

// ---------------------------------------------------------------------------
// VQ-VAE eval forward.  N=65536 points x K=1024 codes x D=64, fp32 in/out.
// Distances via f16x2 split-precision MFMA (16x16x32_f16), numerics as R2:
//   z = zh + 2^-12 zl', e = eh + 2^-12 el'  (lo pre-scaled by 4096)
//   argmax key m = (zh.eh - esq/2) + 2^-12 (zh.el' + zl'.eh)
// R4 structure: 1024 blocks x 256 thr (4 waves = 2 point-groups x 2 K-halves),
// Mtile=32 as two 16-pt tiles sharing B reads, global_load_lds dbuf staging
// with counted vmcnt + single barrier per chunk, A-frags from global, ~38KB
// LDS -> 4 blocks/CU (16 waves/CU), VGPR budget <=128 (launch_bounds(256,4)).
// ---------------------------------------------------------------------------

#define QOUT_SZ  4194304            // 16*64*64*64
#define LOSS_OFF QOUT_SZ
#define IDX_OFF  (QOUT_SZ + 1)
#define PERP_OFF (QOUT_SZ + 1 + 65536)

typedef _Float16 f16x8 __attribute__((ext_vector_type(8)));
typedef _Float16 f16x4 __attribute__((ext_vector_type(4)));
typedef float    f32x4 __attribute__((ext_vector_type(4)));

// ws byte offsets
#define WS_EHI   0          // _Float16[65536] (128 KB)
#define WS_ELO   131072     // _Float16[65536] (128 KB)
#define WS_ESQ   262144     // float[1024]  (stores -0.5*||e||^2)
#define WS_HIST  266240     // float[1024]
#define WS_LOSS  270336     // float[1024]

__device__ __forceinline__ void gll16(const void* g, void* l) {
    __builtin_amdgcn_global_load_lds(
        (const __attribute__((address_space(1))) void*)g,
        (__attribute__((address_space(3))) void*)l, 16, 0, 0);
}

// ---------------------------------------------------------------------------
// Prep: split-convert embedding, esq[k] = -0.5*||e_k||^2, zero hist. 64 x 256.
// ---------------------------------------------------------------------------
__global__ void vq_pre(const float* __restrict__ emb,
                       _Float16* __restrict__ ehi, _Float16* __restrict__ elo,
                       float* __restrict__ esq, float* __restrict__ hist) {
    const int t = threadIdx.x;
    const int g = blockIdx.x * 256 + t;          // float4 unit 0..16383
    float4 v = ((const float4*)emb)[g];
    float xs[4] = {v.x, v.y, v.z, v.w};
    f16x4 hi, lo;
    float ss = 0.f;
#pragma unroll
    for (int j = 0; j < 4; ++j) {
        _Float16 h = (_Float16)xs[j];
        hi[j] = h;
        lo[j] = (_Float16)((xs[j] - (float)h) * 4096.0f);
        ss = fmaf(xs[j], xs[j], ss);
    }
    ((f16x4*)ehi)[g] = hi;
    ((f16x4*)elo)[g] = lo;
    ss += __shfl_xor(ss, 1, 64);
    ss += __shfl_xor(ss, 2, 64);
    ss += __shfl_xor(ss, 4, 64);
    ss += __shfl_xor(ss, 8, 64);
    if ((t & 15) == 0) esq[g >> 4] = -0.5f * ss;
    if (blockIdx.x < 4) hist[blockIdx.x * 256 + t] = 0.f;
}

// ---------------------------------------------------------------------------
// Main distance/argmin/epilogue kernel. 1024 blocks x 256 threads.
// Block owns 64 points (one (b,h) row). Wave (pg,ksel): pg = 32-pt half,
// ksel = 32-code half of each 64-code superchunk. 16 superchunks, dbuf'd.
// ---------------------------------------------------------------------------
__launch_bounds__(256, 4)
__global__ void vq_main(const float* __restrict__ z,
                        const float* __restrict__ emb,
                        const _Float16* __restrict__ gehi,
                        const _Float16* __restrict__ gelo,
                        const float* __restrict__ gesq,
                        float* __restrict__ hist,
                        float* __restrict__ lossp,
                        float* __restrict__ out) {
    __shared__ __align__(16) char es[32768];   // 2 bufs x (hi 8K | lo 8K)
    __shared__ float esql[1024];               // -esq/2
    __shared__ float candv[128];
    __shared__ int   candi[128];
    __shared__ int   idxs[64];
    __shared__ float redw[4];

    const int tid  = threadIdx.x;
    const int blk  = blockIdx.x;               // = b*64 + h
    const int b    = blk >> 6;
    const int h    = blk & 63;
    const int lane = tid & 63;
    const int wv   = tid >> 6;                 // 0..3
    const int pg   = wv & 1;                   // point half (w 0-31 / 32-63)
    const int ksel = wv >> 1;                  // code half of superchunk
    const int col  = lane & 15;
    const int g    = lane >> 4;                // 0..3

    // ---- stage -esq/2 into LDS (coalesced, once) ----
#pragma unroll
    for (int i = 0; i < 4; ++i) esql[tid + 256 * i] = gesq[tid + 256 * i];

    // ---- A fragments straight from global: lane = point row (col) ----
    const float* zb = z + (size_t)b * 262144 + (size_t)h * 64;
    const float* zrow = zb + pg * 32 + col;
    f16x8 Ah[2][2], Al[2][2];
#pragma unroll
    for (int pt = 0; pt < 2; ++pt) {
#pragma unroll
        for (int m = 0; m < 2; ++m) {
#pragma unroll
            for (int j = 0; j < 8; ++j) {
                int c = m * 32 + g * 8 + j;
                float x = zrow[pt * 16 + (size_t)c * 4096];
                _Float16 hh = (_Float16)x;
                Ah[pt][m][j] = hh;
                Al[pt][m][j] = (_Float16)((x - (float)hh) * 4096.0f);
            }
        }
    }

    // ---- staging geometry: superchunk = 64 codes x 128 B per plane ----
    // LDS dest linear in unit u; global source pre-XOR-swizzled (involution).
    const char* gh = (const char*)gehi;
    const char* gl = (const char*)gelo;
    const int u0 = tid, u1 = tid + 256;
    const int c0 = u0 >> 3, c1 = u1 >> 3;
    const size_t so0 = (size_t)c0 * 128 + (size_t)(((u0 & 7) ^ (c0 & 7)) * 16);
    const size_t so1 = (size_t)c1 * 128 + (size_t)(((u1 & 7) ^ (c1 & 7)) * 16);
    char* const dA = es + wv * 1024;           // wave-uniform dest base

#define STAGE(n, bb) do { \
        const size_t gb_ = (size_t)(n) * 8192; \
        char* d_ = dA + (bb) * 16384; \
        gll16(gh + gb_ + so0, d_);            \
        gll16(gh + gb_ + so1, d_ + 4096);     \
        gll16(gl + gb_ + so0, d_ + 8192);     \
        gll16(gl + gb_ + so1, d_ + 12288);    \
    } while (0)

    // ---- per-lane B read offsets (swizzled, loop-invariant) ----
    int rb[2][2];
#pragma unroll
    for (int ct = 0; ct < 2; ++ct) {
        int cl = ksel * 32 + ct * 16 + col;
#pragma unroll
        for (int m = 0; m < 2; ++m)
            rb[ct][m] = cl * 128 + ((((m * 4 + g) * 16)) ^ ((col & 7) << 4));
    }

    float best[2][4];
    int   besti[2][4];
#pragma unroll
    for (int pt = 0; pt < 2; ++pt)
#pragma unroll
        for (int r = 0; r < 4; ++r) { best[pt][r] = -3.4e38f; besti[pt][r] = 0; }

    STAGE(0, 0);

    // ---- k loop: 16 superchunks of 64 codes (each wave uses its 32) ----
    for (int sc = 0; sc < 16; ++sc) {
        const int cur = sc & 1;
        asm volatile("s_waitcnt vmcnt(0)" ::: "memory");
        __builtin_amdgcn_s_barrier();
        asm volatile("" ::: "memory");
        if (sc < 15) STAGE(sc + 1, cur ^ 1);

        const char* bp = es + cur * 16384;
        const int kb = sc * 64 + ksel * 32;
#pragma unroll
        for (int ct = 0; ct < 2; ++ct) {
            const float e2  = esql[kb + ct * 16 + col];
            const int  kidx = kb + ct * 16 + col;
            f16x8 Bh0 = *(const f16x8*)(bp + rb[ct][0]);
            f16x8 Bh1 = *(const f16x8*)(bp + rb[ct][1]);
            f16x8 Bl0 = *(const f16x8*)(bp + 8192 + rb[ct][0]);
            f16x8 Bl1 = *(const f16x8*)(bp + 8192 + rb[ct][1]);
#pragma unroll
            for (int pt = 0; pt < 2; ++pt) {
                f32x4 ah = {e2, e2, e2, e2};
                f32x4 ax = {0.f, 0.f, 0.f, 0.f};
                ah = __builtin_amdgcn_mfma_f32_16x16x32_f16(Ah[pt][0], Bh0, ah, 0, 0, 0);
                ah = __builtin_amdgcn_mfma_f32_16x16x32_f16(Ah[pt][1], Bh1, ah, 0, 0, 0);
                ax = __builtin_amdgcn_mfma_f32_16x16x32_f16(Ah[pt][0], Bl0, ax, 0, 0, 0);
                ax = __builtin_amdgcn_mfma_f32_16x16x32_f16(Ah[pt][1], Bl1, ax, 0, 0, 0);
                ax = __builtin_amdgcn_mfma_f32_16x16x32_f16(Al[pt][0], Bh0, ax, 0, 0, 0);
                ax = __builtin_amdgcn_mfma_f32_16x16x32_f16(Al[pt][1], Bh1, ax, 0, 0, 0);
#pragma unroll
                for (int r = 0; r < 4; ++r) {
                    float mval = fmaf(0x1p-12f, ax[r], ah[r]);
                    if (mval > best[pt][r]) { best[pt][r] = mval; besti[pt][r] = kidx; }
                }
            }
        }
    }
#undef STAGE

    // ---- in-wave argmin over the 16 code-cols (butterfly, np tie-break) ----
#pragma unroll
    for (int mask = 1; mask <= 8; mask <<= 1) {
#pragma unroll
        for (int pt = 0; pt < 2; ++pt)
#pragma unroll
            for (int r = 0; r < 4; ++r) {
                float ov = __shfl_xor(best[pt][r], mask, 64);
                int   oi = __shfl_xor(besti[pt][r], mask, 64);
                if (ov > best[pt][r] ||
                    (ov == best[pt][r] && oi < besti[pt][r])) {
                    best[pt][r] = ov; besti[pt][r] = oi;
                }
            }
    }
    if (col == 0) {
#pragma unroll
        for (int pt = 0; pt < 2; ++pt)
#pragma unroll
            for (int r = 0; r < 4; ++r) {
                int p = pg * 32 + pt * 16 + g * 4 + r;
                candv[p * 2 + ksel] = best[pt][r];
                candi[p * 2 + ksel] = besti[pt][r];
            }
    }
    __syncthreads();

    // ---- combine the two K-halves, write idx, histogram ----
    if (tid < 64) {
        float v0 = candv[tid * 2],     v1 = candv[tid * 2 + 1];
        int   i0 = candi[tid * 2],     i1 = candi[tid * 2 + 1];
        int bi = (v1 > v0 || (v1 == v0 && i1 < i0)) ? i1 : i0;
        idxs[tid] = bi;
        atomicAdd(&hist[bi], 1.0f);               // exact int counts
        out[(size_t)IDX_OFF + blk * 64 + tid] = (float)bi;
    }
    __syncthreads();

    // ---- epilogue: quantized write (coalesced over w) + loss partial ----
    const int w  = tid & 63;
    const int cq = tid >> 6;                      // channels cq*16..cq*16+15
    const int idx = idxs[w];
    const float* ev = emb + (size_t)idx * 64 + cq * 16;
    const float* zr = zb + w;
    float* outq = out + (size_t)b * 262144 + (size_t)h * 64 + w;
    float lsum = 0.f;
#pragma unroll
    for (int i = 0; i < 4; ++i) {
        float4 qv = *(const float4*)(ev + i * 4);
        float q4[4] = {qv.x, qv.y, qv.z, qv.w};
#pragma unroll
        for (int jj = 0; jj < 4; ++jj) {
            int c = cq * 16 + i * 4 + jj;
            float zv = zr[(size_t)c * 4096];      // L3-hot re-read
            outq[(size_t)c * 4096] = q4[jj];
            float d = q4[jj] - zv;
            lsum = fmaf(d, d, lsum);
        }
    }
#pragma unroll
    for (int off = 32; off > 0; off >>= 1)
        lsum += __shfl_xor(lsum, off, 64);
    if (lane == 0) redw[wv] = lsum;
    __syncthreads();
    if (tid == 0)
        lossp[blk] = redw[0] + redw[1] + redw[2] + redw[3];
}

// ---------------------------------------------------------------------------
// Finalize: loss + perplexity, fixed-order tree. 1 x 1024.
// ---------------------------------------------------------------------------
__global__ void vq_fin(const float* __restrict__ hist,
                       const float* __restrict__ lossp,
                       float* __restrict__ out) {
    __shared__ float sh[1024];
    __shared__ float sl[1024];
    int t = threadIdx.x;
    float hc = hist[t];
    float p  = hc * (1.0f / 65536.0f);
    sh[t] = p * logf(p + 1e-10f);
    sl[t] = lossp[t];
    __syncthreads();
    for (int s = 512; s > 0; s >>= 1) {
        if (t < s) { sh[t] += sh[t + s]; sl[t] += sl[t + s]; }
        __syncthreads();
    }
    if (t == 0) {
        out[LOSS_OFF] = 0.25f * sl[0] / (float)QOUT_SZ;
        out[PERP_OFF] = expf(-sh[0]);
    }
}

extern "C" void kernel_launch(void* const* d_in, const int* in_sizes, int n_in,
                              void* d_out, int out_size, void* d_ws, size_t ws_size,
                              hipStream_t stream) {
    const float* z   = (const float*)d_in[0];   // [16,64,64,64] fp32 NCHW
    const float* emb = (const float*)d_in[1];   // [1024,64] fp32
    float* out = (float*)d_out;
    char*  ws  = (char*)d_ws;

    _Float16* ehi   = (_Float16*)(ws + WS_EHI);
    _Float16* elo   = (_Float16*)(ws + WS_ELO);
    float*    esq   = (float*)(ws + WS_ESQ);
    float*    hist  = (float*)(ws + WS_HIST);
    float*    lossp = (float*)(ws + WS_LOSS);

    vq_pre<<<64, 256, 0, stream>>>(emb, ehi, elo, esq, hist);
    vq_main<<<1024, 256, 0, stream>>>(z, emb, ehi, elo, esq, hist, lossp, out);
    vq_fin<<<1, 1024, 0, stream>>>(hist, lossp, out);
}